// Round 1
// baseline (398.523 us; speedup 1.0000x reference)
//
#include <hip/hip_runtime.h>

// irreps Linear: out[n, off_l + w*d + i] = 0.125 * sum_u x[n, off_l + u*d + i] * Wl[u][w]
// N=262144 rows of 576 = [64x(d=1) | 64x(d=3) | 64x(d=5)].
// Memory-bound (1.21 GB @ ~6.3 TB/s => ~192 us floor). f16 MFMA 16x16x16 (classic,
// unambiguous fragment layout) keeps VALU free for streaming/conversion.

typedef _Float16 half4  __attribute__((ext_vector_type(4)));
typedef float    f32x4  __attribute__((ext_vector_type(4)));
typedef float    fltx4  __attribute__((ext_vector_type(4)));
typedef unsigned int u32x4 __attribute__((ext_vector_type(4)));

#define RPB     32                  // rows per block
#define NROWS   262144
#define XTILE_ROWS 288              // 32*1 + 32*3 + 32*5 rows of 64 f16 (128 B each)
#define WBASE   (XTILE_ROWS * 128)  // 36864
#define WBYTES  (3 * 64 * 128)      // 24576 (3 matrices, 64 rows x 128 B)
#define LDS_BYTES (WBASE + WBYTES)  // 61440 -> 2 blocks/CU

// ---- prep: W[u][w] fp32 -> ws image: per l, row w (64 rows x 128B), col u, f16,
// with the same XOR swizzle the main kernel uses for all 128B-stride LDS rows.
__global__ __launch_bounds__(256) void prep_weights(
    const float* __restrict__ w0, const float* __restrict__ w1,
    const float* __restrict__ w2, unsigned char* __restrict__ ws) {
  int idx = blockIdx.x * 256 + threadIdx.x;   // 0..12287
  if (idx >= 3 * 4096) return;
  int l = idx >> 12;
  int rem = idx & 4095;                        // rem = u*64 + w  (coalesced read)
  int u = rem >> 6, w = rem & 63;
  const float* W = (l == 0) ? w0 : ((l == 1) ? w1 : w2);
  _Float16 v = (_Float16)W[rem];
  int byte = l * 8192 + ((w * 128 + u * 2) ^ ((w & 7) << 4));
  *(_Float16*)(ws + byte) = v;
}

// stage one l-segment of the x tile into LDS as f16, rows = (n_local*d + i), cols = u
template<int D, int OFF, int SEGROW, int F4PR>
__device__ __forceinline__ void stage_seg(unsigned char* lds, const float* __restrict__ xrow0, int tid) {
  // F4PR = float4s per row in this segment (16/48/80); 32*F4PR total, 256 threads
  for (int t = tid; t < RPB * F4PR; t += 256) {
    int row = t / F4PR;                 // const divisor
    int f4  = t - row * F4PR;
    fltx4 v = *(const fltx4*)(xrow0 + (long long)row * 576 + OFF + f4 * 4);
    int idx = f4 * 4;                   // element index within segment (= u*D + i)
#pragma unroll
    for (int j = 0; j < 4; ++j) {
      int u = (idx + j) / D;            // const divisor
      int i = (idx + j) - u * D;
      int lrow = SEGROW + row * D + i;
      int b = (lrow * 128 + u * 2) ^ ((lrow & 7) << 4);
      *(_Float16*)(lds + b) = (_Float16)v[j];
    }
  }
}

// compute all 16x16 output tiles of one l-segment; MT m-tiles x 4 w-tiles
template<int D, int OFF, int SEGROW, int MT, int L>
__device__ __forceinline__ void compute_seg(const unsigned char* lds, float* __restrict__ out,
                                            int n0, int wave, int lane) {
  const int lane15 = lane & 15;
  const int laneq  = lane >> 4;
  const int coff   = laneq * 8;         // k-chunk byte offset within a row
  for (int t = wave; t < MT * 4; t += 4) {
    int mt = t >> 2, wt = t & 3;
    // A: lane holds row m = lane%16 of the m-tile, k = 4*(lane/16)+j (per s-step)
    int arow  = SEGROW + mt * 16 + lane15;
    int abase = arow * 128;
    int aswz  = (arow & 7) << 4;
    // B: lane holds col n(=w) = lane%16, same k grouping; Wt rows are w
    int brow  = wt * 16 + lane15;
    int bbase = WBASE + L * 8192 + brow * 128;
    int bswz  = (brow & 7) << 4;
    f32x4 acc = {0.f, 0.f, 0.f, 0.f};
#pragma unroll
    for (int s = 0; s < 4; ++s) {
      half4 a = *(const half4*)(lds + abase + ((s * 32 + coff) ^ aswz));
      half4 b = *(const half4*)(lds + bbase - WBASE - L * 8192 + WBASE + L * 8192 + ((s * 32 + coff) ^ bswz));
      acc = __builtin_amdgcn_mfma_f32_16x16x16f16(a, b, acc, 0, 0, 0);
    }
    // D: col = lane&15 (w), row = 4*(lane>>4) + reg  [HW-verified mapping]
    int w  = wt * 16 + lane15;
    int r0 = mt * 16 + laneq * 4;
#pragma unroll
    for (int j = 0; j < 4; ++j) {
      int r = r0 + j;
      int n = r / D;                    // const divisor
      int i = r - n * D;
      out[(long long)(n0 + n) * 576 + OFF + w * D + i] = 0.125f * acc[j];
    }
  }
}

__global__ __launch_bounds__(256, 2) void linear_irreps(
    const float* __restrict__ x,
    const float* __restrict__ w0, const float* __restrict__ w1, const float* __restrict__ w2,
    const unsigned char* __restrict__ ws, int use_ws,
    float* __restrict__ out) {
  __shared__ __align__(16) unsigned char lds[LDS_BYTES];
  const int tid = threadIdx.x;
  const long long base = (long long)blockIdx.x * (RPB * 576);

  // ---- stage x tile (contiguous 72KB global span -> f16 LDS, transposed to [row(n,i)][u])
  stage_seg<1,   0,   0, 16>(lds, x + base, tid);
  stage_seg<3,  64,  32, 48>(lds, x + base, tid);
  stage_seg<5, 256, 128, 80>(lds, x + base, tid);

  // ---- weights -> LDS
  if (use_ws) {
    const u32x4* src = (const u32x4*)ws;
    u32x4* dst = (u32x4*)(lds + WBASE);
    for (int t = tid; t < WBYTES / 16; t += 256) dst[t] = src[t];   // 6 iters, L2-hot
  } else {
    for (int t = tid; t < 3 * 4096; t += 256) {
      int l = t >> 12;
      int rem = t & 4095;
      int u = rem >> 6, w = rem & 63;
      const float* W = (l == 0) ? w0 : ((l == 1) ? w1 : w2);
      _Float16 v = (_Float16)W[rem];
      int byte = WBASE + l * 8192 + ((w * 128 + u * 2) ^ ((w & 7) << 4));
      *(_Float16*)(lds + byte) = v;
    }
  }
  __syncthreads();

  // ---- MFMA + direct stores
  const int wave = tid >> 6, lane = tid & 63;
  const int n0 = blockIdx.x * RPB;
  compute_seg<1,   0,   0,  2, 0>(lds, out, n0, wave, lane);
  compute_seg<3,  64,  32,  6, 1>(lds, out, n0, wave, lane);
  compute_seg<5, 256, 128, 10, 2>(lds, out, n0, wave, lane);
}

extern "C" void kernel_launch(void* const* d_in, const int* in_sizes, int n_in,
                              void* d_out, int out_size, void* d_ws, size_t ws_size,
                              hipStream_t stream) {
  const float* x  = (const float*)d_in[0];
  const float* w0 = (const float*)d_in[1];
  const float* w1 = (const float*)d_in[2];
  const float* w2 = (const float*)d_in[3];
  float* out = (float*)d_out;

  int use_ws = (ws_size >= (size_t)WBYTES) ? 1 : 0;
  if (use_ws) {
    prep_weights<<<48, 256, 0, stream>>>(w0, w1, w2, (unsigned char*)d_ws);
  }
  linear_irreps<<<NROWS / RPB, 256, 0, stream>>>(
      x, w0, w1, w2, (const unsigned char*)d_ws, use_ws, out);
}